// Round 1
// baseline (121.757 us; speedup 1.0000x reference)
//
#include <hip/hip_runtime.h>

#define NODES 128   // nodes per graph (block size n)
#define FEAT  32    // feature dim
#define WPAD  36    // LDS row stride for W chunk: 32 k-floats + 4 pad (keeps 16B align, breaks bank aliasing)

// One 128-thread block (2 waves) per batch element.
// Thread tile: 8 rows x 4 feats. W staged in 4 chunks of 32 k-columns.
__global__ __launch_bounds__(128)
void blockdiag_mm(const float* __restrict__ inp,
                  const float* __restrict__ weights,
                  const int* __restrict__ idx,
                  float* __restrict__ out)
{
    __shared__ __align__(16) float xs[NODES * FEAT];   // 16 KiB: x_b, [k][f] row-major
    __shared__ __align__(16) float ws[NODES * WPAD];   // 18 KiB: W rows x current 32-k chunk

    const int b    = blockIdx.x;
    const int u    = threadIdx.x;                  // 0..127
    const int rowg = (u & 7) | ((u >> 6) << 3);    // 0..15: lane%8 + 8*wave
    const int tf   = (u >> 3) & 7;                 // 0..7 feature group
    const int f0   = tf << 2;

    const float* __restrict__ xin = inp + (size_t)b * (NODES * FEAT);
    const float* __restrict__ wb  = weights + (size_t)idx[b] * (NODES * NODES);

    // stage x_b: 16 KiB, fully coalesced float4
    {
        const float4* src = (const float4*)xin;
        float4* dst = (float4*)xs;
        #pragma unroll
        for (int s = 0; s < 8; ++s)
            dst[s * 128 + u] = src[s * 128 + u];
    }

    float4 acc[8];
    #pragma unroll
    for (int r = 0; r < 8; ++r) acc[r] = make_float4(0.f, 0.f, 0.f, 0.f);

    const int kk = u & 7;    // staging: which float4 within the 32-k chunk
    const int ib = u >> 3;   // staging: base row 0..15

    for (int c = 0; c < 4; ++c) {
        const int k0 = c * 32;
        // stage W chunk: all 128 rows, k-columns k0..k0+31 (8 rows x 128B per wave-instr)
        #pragma unroll
        for (int s = 0; s < 8; ++s) {
            const int i = ib + (s << 4);
            const float4 v = *(const float4*)(wb + i * NODES + k0 + (kk << 2));
            *(float4*)(ws + i * WPAD + (kk << 2)) = v;
        }
        __syncthreads();

        #pragma unroll
        for (int kc = 0; kc < 8; ++kc) {
            // b-vectors: x[k..k+3][f0..f0+3] — 8 distinct addrs/wave, banks spread, 8-way broadcast
            const float4 bv0 = *(const float4*)(xs + (k0 + kc * 4 + 0) * FEAT + f0);
            const float4 bv1 = *(const float4*)(xs + (k0 + kc * 4 + 1) * FEAT + f0);
            const float4 bv2 = *(const float4*)(xs + (k0 + kc * 4 + 2) * FEAT + f0);
            const float4 bv3 = *(const float4*)(xs + (k0 + kc * 4 + 3) * FEAT + f0);
            #pragma unroll
            for (int r = 0; r < 8; ++r) {
                // a-vector: W[rowg+16r][4 consecutive k] — stride 36 floats => banks 4*rowg, conflict-free
                const float4 av = *(const float4*)(ws + (rowg + 16 * r) * WPAD + (kc << 2));
                acc[r].x += av.x * bv0.x; acc[r].y += av.x * bv0.y; acc[r].z += av.x * bv0.z; acc[r].w += av.x * bv0.w;
                acc[r].x += av.y * bv1.x; acc[r].y += av.y * bv1.y; acc[r].z += av.y * bv1.z; acc[r].w += av.y * bv1.w;
                acc[r].x += av.z * bv2.x; acc[r].y += av.z * bv2.y; acc[r].z += av.z * bv2.z; acc[r].w += av.z * bv2.w;
                acc[r].x += av.w * bv3.x; acc[r].y += av.w * bv3.y; acc[r].z += av.w * bv3.z; acc[r].w += av.w * bv3.w;
            }
        }
        __syncthreads();
    }

    // write out: per wave the 64 float4 stores cover one contiguous 1 KiB span per r
    float* ob = out + (size_t)b * (NODES * FEAT);
    #pragma unroll
    for (int r = 0; r < 8; ++r)
        *(float4*)(ob + (rowg + 16 * r) * FEAT + f0) = acc[r];
}

extern "C" void kernel_launch(void* const* d_in, const int* in_sizes, int n_in,
                              void* d_out, int out_size, void* d_ws, size_t ws_size,
                              hipStream_t stream) {
    const float* inp = (const float*)d_in[0];
    const float* wts = (const float*)d_in[1];
    const int*   idx = (const int*)d_in[2];
    float* outp = (float*)d_out;
    const int B = in_sizes[2];   // 1024 batch elements
    hipLaunchKernelGGL(blockdiag_mm, dim3(B), dim3(128), 0, stream,
                       inp, wts, idx, outp);
}

// Round 2
// 118.751 us; speedup vs baseline: 1.0253x; 1.0253x over previous
//
#include <hip/hip_runtime.h>

#define NODES 128   // nodes per graph
#define FEAT  32    // feature dim
#define CK    16    // k-columns per W chunk
#define NCH   (NODES / CK)   // 8 chunks

typedef const __attribute__((address_space(1))) void gvoid;
typedef __attribute__((address_space(3))) void       svoid;

// One 256-thread block (4 waves) per batch element. grid=1024 -> 4 blocks/CU,
// 16 waves/CU. LDS = 16 KiB x + 2x8 KiB W double-buffer = 32 KiB (cap 5 blocks/CU).
// W staged via async global_load_lds (16B) with XOR-swizzled columns
// (k4' = k4 ^ (row&3)) so LDS reads avoid >2-way bank aliasing without padding
// (padding breaks global_load_lds's contiguous wave-uniform-base+lane*16 dest).
__global__ __launch_bounds__(256, 4)
void blockdiag_mm(const float* __restrict__ inp,
                  const float* __restrict__ weights,
                  const int* __restrict__ idx,
                  float* __restrict__ out)
{
    __shared__ __align__(16) float xs[NODES * FEAT];    // 16 KiB, [k][f]
    __shared__ __align__(16) float ws[2][NODES * CK];   // 2 x 8 KiB, [row][swizzled k4]

    const int b    = blockIdx.x;
    const int u    = threadIdx.x;      // 0..255
    const int w    = u >> 6;           // wave 0..3
    const int f0   = (u & 7) << 2;     // feature quad
    const int rowb = u >> 3;           // 0..31; thread rows = rowb + 32*r
    const int swz  = rowb & 3;

    const float* __restrict__ xin = inp + (size_t)b * (NODES * FEAT);
    const float* __restrict__ wb  = weights + (size_t)idx[b] * (NODES * NODES);

    // ---- async stage x: 1024 float4, contiguous, 4 wave-rounds
    #pragma unroll
    for (int s = 0; s < 4; ++s) {
        gvoid* g = (gvoid*)(xin + (s * 256 + u) * 4);
        svoid* l = (svoid*)(xs + (s * 256 + w * 64) * 4);  // wave-uniform base
        __builtin_amdgcn_global_load_lds(g, l, 16, 0, 0);
    }

    // ---- async stage one 16-k W chunk (512 float4) into buffer p
    auto stage_w = [&](int c, int p) {
        #pragma unroll
        for (int s = 0; s < 2; ++s) {
            const int d4  = s * 256 + u;     // dest float4 index in chunk
            const int row = d4 >> 2;         // 4 float4 per row
            const int c4  = d4 & 3;
            const int k4  = c4 ^ (row & 3);  // XOR column swizzle
            gvoid* g = (gvoid*)(wb + row * NODES + c * CK + (k4 << 2));
            svoid* l = (svoid*)(&ws[p][0] + (s * 256 + w * 64) * 4);
            __builtin_amdgcn_global_load_lds(g, l, 16, 0, 0);
        }
    };

    stage_w(0, 0);

    float4 acc[4];
    #pragma unroll
    for (int r = 0; r < 4; ++r) acc[r] = make_float4(0.f, 0.f, 0.f, 0.f);

    __syncthreads();   // vmcnt(0) drain: x + chunk0 resident

    for (int c = 0; c < NCH; ++c) {
        if (c + 1 < NCH) stage_w(c + 1, (c + 1) & 1);   // prefetch overlaps compute below
        const float* __restrict__ wsp = &ws[c & 1][0];

        #pragma unroll
        for (int kc = 0; kc < 4; ++kc) {
            const int kb = c * CK + kc * 4;
            const float4 bv0 = *(const float4*)(xs + (kb + 0) * FEAT + f0);
            const float4 bv1 = *(const float4*)(xs + (kb + 1) * FEAT + f0);
            const float4 bv2 = *(const float4*)(xs + (kb + 2) * FEAT + f0);
            const float4 bv3 = *(const float4*)(xs + (kb + 3) * FEAT + f0);
            const int cidx = (kc ^ swz) << 2;
            #pragma unroll
            for (int r = 0; r < 4; ++r) {
                const float4 av = *(const float4*)(wsp + (rowb + 32 * r) * CK + cidx);
                acc[r].x += av.x * bv0.x; acc[r].y += av.x * bv0.y; acc[r].z += av.x * bv0.z; acc[r].w += av.x * bv0.w;
                acc[r].x += av.y * bv1.x; acc[r].y += av.y * bv1.y; acc[r].z += av.y * bv1.z; acc[r].w += av.y * bv1.w;
                acc[r].x += av.z * bv2.x; acc[r].y += av.z * bv2.y; acc[r].z += av.z * bv2.z; acc[r].w += av.z * bv2.w;
                acc[r].x += av.w * bv3.x; acc[r].y += av.w * bv3.y; acc[r].z += av.w * bv3.z; acc[r].w += av.w * bv3.w;
            }
        }
        __syncthreads();   // drains prefetch vmcnt + guards buffer reuse
    }

    // ---- store: per wave & r, 8 rows x 32 feats = contiguous 1 KiB
    float* ob = out + (size_t)b * (NODES * FEAT);
    #pragma unroll
    for (int r = 0; r < 4; ++r)
        *(float4*)(ob + (rowb + 32 * r) * FEAT + f0) = acc[r];
}

extern "C" void kernel_launch(void* const* d_in, const int* in_sizes, int n_in,
                              void* d_out, int out_size, void* d_ws, size_t ws_size,
                              hipStream_t stream) {
    const float* inp = (const float*)d_in[0];
    const float* wts = (const float*)d_in[1];
    const int*   idx = (const int*)d_in[2];
    float* outp = (float*)d_out;
    const int B = in_sizes[2];   // 1024
    hipLaunchKernelGGL(blockdiag_mm, dim3(B), dim3(256), 0, stream,
                       inp, wts, idx, outp);
}

// Round 3
// 112.215 us; speedup vs baseline: 1.0850x; 1.0582x over previous
//
#include <hip/hip_runtime.h>

#define NODES 128
#define FEAT  32
#define XPAD  136   // XT row stride in bf16 elems (128 + 8 pad)

typedef __attribute__((ext_vector_type(8))) short bf16x8;
typedef __attribute__((ext_vector_type(4))) float f32x4;

// RNE fp32->bf16 pack of two floats into one dword (lo = a, hi = b)
__device__ __forceinline__ unsigned pk_bf16(float a, float b) {
    unsigned ua = __builtin_bit_cast(unsigned, a);
    unsigned ub = __builtin_bit_cast(unsigned, b);
    ua += 0x7fffu + ((ua >> 16) & 1u);
    ub += 0x7fffu + ((ub >> 16) & 1u);
    return (ua >> 16) | (ub & 0xffff0000u);
}

__device__ __forceinline__ bf16x8 cvt_frag(float4 lo, float4 hi) {
    union { unsigned u[4]; bf16x8 v; } r;
    r.u[0] = pk_bf16(lo.x, lo.y);
    r.u[1] = pk_bf16(lo.z, lo.w);
    r.u[2] = pk_bf16(hi.x, hi.y);
    r.u[3] = pk_bf16(hi.z, hi.w);
    return r.v;
}

// One 256-thread block (4 waves) per batch element. Wave w computes output
// rows 32w..32w+31 (all 32 feats) as 2x2 mfma_f32_16x16x32_bf16 tiles over
// a 4-chunk k-loop. W rows are wave-exclusive -> A-frags load DIRECTLY from
// global (fp32, 8 consecutive floats/lane) and convert in-register; only X
// is staged in LDS (transposed, bf16) for contiguous B-frag ds_read_b128.
// Single __syncthreads in the whole kernel.
__global__ __launch_bounds__(256, 4)
void blockdiag_mm(const float* __restrict__ inp,
                  const float* __restrict__ weights,
                  const int* __restrict__ idx,
                  float* __restrict__ out)
{
    __shared__ __align__(16) short xt[FEAT * XPAD];  // 8.5 KiB: XT[f][k] bf16

    const int b  = blockIdx.x;
    const int u  = threadIdx.x;
    const int w  = u >> 6;        // wave 0..3
    const int l  = u & 63;        // lane
    const int ln = l & 15;        // m/n index within 16-tile
    const int q  = l >> 4;        // k-quad 0..3

    const float* __restrict__ xin = inp + (size_t)b * (NODES * FEAT);
    const float* __restrict__ wb  = weights + (size_t)idx[b] * (NODES * NODES);

    // ---- prefetch A for kc=0: lane reads W[32w+16mt+ln][q*8 .. q*8+7]
    float4 a_cur[2][2], a_nxt[2][2];
    #pragma unroll
    for (int mt = 0; mt < 2; ++mt) {
        const float* r = wb + (32 * w + 16 * mt + ln) * NODES + q * 8;
        a_cur[mt][0] = *(const float4*)(r);
        a_cur[mt][1] = *(const float4*)(r + 4);
    }

    // ---- stage XT (bf16, transposed): X[k][f] -> XT[f][k]
    {
        const float4* x4 = (const float4*)xin;
        const int fq = u & 7;            // feature quad (f0 = 4*fq)
        const int kh = (u >> 3) & 31;    // k-pair index
        #pragma unroll
        for (int rr = 0; rr < 2; ++rr) {
            const int k0 = rr * 64 + kh * 2;
            float4 v0 = x4[k0 * 8 + fq];
            float4 v1 = x4[(k0 + 1) * 8 + fq];
            const float pv0[4] = {v0.x, v0.y, v0.z, v0.w};
            const float pv1[4] = {v1.x, v1.y, v1.z, v1.w};
            #pragma unroll
            for (int i = 0; i < 4; ++i)
                *(unsigned*)(&xt[(fq * 4 + i) * XPAD + k0]) = pk_bf16(pv0[i], pv1[i]);
        }
    }
    __syncthreads();

    f32x4 acc[2][2] = {};

    #pragma unroll
    for (int kc = 0; kc < 4; ++kc) {
        if (kc < 3) {   // prefetch next k-chunk's A while computing this one
            #pragma unroll
            for (int mt = 0; mt < 2; ++mt) {
                const float* r = wb + (32 * w + 16 * mt + ln) * NODES + (kc + 1) * 32 + q * 8;
                a_nxt[mt][0] = *(const float4*)(r);
                a_nxt[mt][1] = *(const float4*)(r + 4);
            }
        }
        bf16x8 bfr[2];
        #pragma unroll
        for (int nt = 0; nt < 2; ++nt)
            bfr[nt] = *(const bf16x8*)(&xt[(16 * nt + ln) * XPAD + kc * 32 + q * 8]);
        bf16x8 afr[2];
        #pragma unroll
        for (int mt = 0; mt < 2; ++mt)
            afr[mt] = cvt_frag(a_cur[mt][0], a_cur[mt][1]);
        #pragma unroll
        for (int mt = 0; mt < 2; ++mt)
            #pragma unroll
            for (int nt = 0; nt < 2; ++nt)
                acc[mt][nt] = __builtin_amdgcn_mfma_f32_16x16x32_bf16(
                    afr[mt], bfr[nt], acc[mt][nt], 0, 0, 0);
        #pragma unroll
        for (int mt = 0; mt < 2; ++mt) {
            a_cur[mt][0] = a_nxt[mt][0];
            a_cur[mt][1] = a_nxt[mt][1];
        }
    }

    // ---- store: D layout col=lane&15, row=(lane>>4)*4+reg (m89-verified)
    float* ob = out + (size_t)b * (NODES * FEAT);
    #pragma unroll
    for (int mt = 0; mt < 2; ++mt)
        #pragma unroll
        for (int nt = 0; nt < 2; ++nt)
            #pragma unroll
            for (int reg = 0; reg < 4; ++reg)
                ob[(32 * w + 16 * mt + q * 4 + reg) * FEAT + 16 * nt + ln] = acc[mt][nt][reg];
}

extern "C" void kernel_launch(void* const* d_in, const int* in_sizes, int n_in,
                              void* d_out, int out_size, void* d_ws, size_t ws_size,
                              hipStream_t stream) {
    const float* inp = (const float*)d_in[0];
    const float* wts = (const float*)d_in[1];
    const int*   idx = (const int*)d_in[2];
    float* outp = (float*)d_out;
    const int B = in_sizes[2];   // 1024
    hipLaunchKernelGGL(blockdiag_mm, dim3(B), dim3(256), 0, stream,
                       inp, wts, idx, outp);
}

// Round 4
// 110.263 us; speedup vs baseline: 1.1042x; 1.0177x over previous
//
#include <hip/hip_runtime.h>

#define NODES 128
#define FEAT  32
#define XPAD  136   // XT row stride in bf16 elems (128 + 8 pad -> 272B rows, 2-way-max bank alias = free)

typedef __attribute__((ext_vector_type(8))) short bf16x8;
typedef __attribute__((ext_vector_type(4))) float f32x4;

// RNE fp32->bf16 pack of two floats into one dword (lo = a, hi = b)
__device__ __forceinline__ unsigned pk_bf16(float a, float b) {
    unsigned ua = __builtin_bit_cast(unsigned, a);
    unsigned ub = __builtin_bit_cast(unsigned, b);
    ua += 0x7fffu + ((ua >> 16) & 1u);
    ub += 0x7fffu + ((ub >> 16) & 1u);
    return (ua >> 16) | (ub & 0xffff0000u);
}

__device__ __forceinline__ bf16x8 cvt_frag(float4 lo, float4 hi) {
    union { unsigned u[4]; bf16x8 v; } r;
    r.u[0] = pk_bf16(lo.x, lo.y);
    r.u[1] = pk_bf16(lo.z, lo.w);
    r.u[2] = pk_bf16(hi.x, hi.y);
    r.u[3] = pk_bf16(hi.z, hi.w);
    return r.v;
}

// One 512-thread block (8 waves) per batch element; wave w owns output rows
// 16w..16w+15 (1x2 mfma_f32_16x16x32_bf16 tiles, 4-chunk k-loop).
// 8192 waves total = 32 waves/CU (HW max) for latency hiding.
// ALL A-fragments (full 128-k strip, 8 dwordx4/lane) are prefetched at kernel
// entry -> single latency exposure, overlapped by X staging + barrier.
// Only X goes through LDS (bf16, transposed). One __syncthreads total.
__global__ __launch_bounds__(512, 8)
void blockdiag_mm(const float* __restrict__ inp,
                  const float* __restrict__ weights,
                  const int* __restrict__ idx,
                  float* __restrict__ out)
{
    __shared__ __align__(16) short xt[FEAT * XPAD];  // 8.5 KiB: XT[f][k] bf16

    const int b  = blockIdx.x;
    const int u  = threadIdx.x;   // 0..511
    const int w  = u >> 6;        // wave 0..7
    const int l  = u & 63;
    const int ln = l & 15;        // row within 16-tile / output col lane
    const int q  = l >> 4;        // k-quad 0..3

    const float* __restrict__ xin = inp + (size_t)b * (NODES * FEAT);
    const float* __restrict__ wb  = weights + (size_t)idx[b] * (NODES * NODES);

    // ---- prefetch ALL A: lane's row = 16w+ln, k strips q*8+32*kc, kc=0..3
    float4 a[4][2];
    {
        const float* ar = wb + (16 * w + ln) * NODES + q * 8;
        #pragma unroll
        for (int kc = 0; kc < 4; ++kc) {
            a[kc][0] = *(const float4*)(ar + kc * 32);
            a[kc][1] = *(const float4*)(ar + kc * 32 + 4);
        }
    }

    // ---- stage XT (bf16, transposed): X[k][f] -> XT[f][k]; 2 float4 loads/thread
    {
        const float4* x4 = (const float4*)xin;
        const int fq = u & 7;        // feature quad
        const int k0 = (u >> 3) * 2; // 0,2,..,126
        float4 v0 = x4[k0 * 8 + fq];
        float4 v1 = x4[(k0 + 1) * 8 + fq];
        const float pv0[4] = {v0.x, v0.y, v0.z, v0.w};
        const float pv1[4] = {v1.x, v1.y, v1.z, v1.w};
        #pragma unroll
        for (int i = 0; i < 4; ++i)
            *(unsigned*)(&xt[(fq * 4 + i) * XPAD + k0]) = pk_bf16(pv0[i], pv1[i]);
    }
    __syncthreads();

    f32x4 acc[2] = {};

    #pragma unroll
    for (int kc = 0; kc < 4; ++kc) {
        const bf16x8 afr = cvt_frag(a[kc][0], a[kc][1]);
        #pragma unroll
        for (int nt = 0; nt < 2; ++nt) {
            const bf16x8 bfr = *(const bf16x8*)(&xt[(16 * nt + ln) * XPAD + kc * 32 + q * 8]);
            acc[nt] = __builtin_amdgcn_mfma_f32_16x16x32_bf16(afr, bfr, acc[nt], 0, 0, 0);
        }
    }

    // ---- store: D layout col=lane&15, row=(lane>>4)*4+reg (m89-verified)
    float* ob = out + (size_t)b * (NODES * FEAT);
    #pragma unroll
    for (int nt = 0; nt < 2; ++nt)
        #pragma unroll
        for (int reg = 0; reg < 4; ++reg)
            ob[(16 * w + q * 4 + reg) * FEAT + 16 * nt + ln] = acc[nt][reg];
}

extern "C" void kernel_launch(void* const* d_in, const int* in_sizes, int n_in,
                              void* d_out, int out_size, void* d_ws, size_t ws_size,
                              hipStream_t stream) {
    const float* inp = (const float*)d_in[0];
    const float* wts = (const float*)d_in[1];
    const int*   idx = (const int*)d_in[2];
    float* outp = (float*)d_out;
    const int B = in_sizes[2];   // 1024
    hipLaunchKernelGGL(blockdiag_mm, dim3(B), dim3(512), 0, stream,
                       inp, wts, idx, outp);
}

// Round 5
// 108.593 us; speedup vs baseline: 1.1212x; 1.0154x over previous
//
#include <hip/hip_runtime.h>

#define NODES 128
#define FEAT  32
#define XPAD  136   // XT row stride (bf16 elems): 272B rows -> conflict-free B-frag ds_read_b128

typedef __attribute__((ext_vector_type(8))) short bf16x8;
typedef __attribute__((ext_vector_type(4))) float f32x4;

typedef const __attribute__((address_space(1))) void gvoid;
typedef __attribute__((address_space(3))) void       svoid;

// RNE fp32->bf16 pack of two floats into one dword (lo = a, hi = b)
__device__ __forceinline__ unsigned pk_bf16(float a, float b) {
    unsigned ua = __builtin_bit_cast(unsigned, a);
    unsigned ub = __builtin_bit_cast(unsigned, b);
    ua += 0x7fffu + ((ua >> 16) & 1u);
    ub += 0x7fffu + ((ub >> 16) & 1u);
    return (ua >> 16) | (ub & 0xffff0000u);
}

__device__ __forceinline__ bf16x8 cvt_frag(float4 lo, float4 hi) {
    union { unsigned u[4]; bf16x8 v; } r;
    r.u[0] = pk_bf16(lo.x, lo.y);
    r.u[1] = pk_bf16(lo.z, lo.w);
    r.u[2] = pk_bf16(hi.x, hi.y);
    r.u[3] = pk_bf16(hi.z, hi.w);
    return r.v;
}

// One 512-thread block (8 waves) per batch element; wave w owns output rows
// 16w..16w+15. W is staged into LDS by async global_load_lds (width=16, no
// VGPR round-trip, deep DMA queue) in two 64-k-column phases of 32 KB.
// LDS W layout: row-major, 16 x 16B segs/row, seg ROTATED by row
// (lseg=(gseg+row)&15) via the DMA *source* address (dest must stay
// contiguous) -> A-frag ds_read_b128 hits all 8 bank-groups uniformly.
// X staged once (bf16, transposed, padded). LDS 40.5 KB -> 3 blocks/CU,
// 24 waves/CU; VGPR small -> __launch_bounds__(512,6).
__global__ __launch_bounds__(512, 6)
void blockdiag_mm(const float* __restrict__ inp,
                  const float* __restrict__ weights,
                  const int* __restrict__ idx,
                  float* __restrict__ out)
{
    __shared__ __align__(16) float4 wc[NODES * 16];   // 32 KiB: current W k-chunk
    __shared__ __align__(16) short  xt[FEAT * XPAD];  // 8.5 KiB: XT[f][k] bf16

    const int b  = blockIdx.x;
    const int u  = threadIdx.x;   // 0..511
    const int w  = u >> 6;        // wave 0..7
    const int l  = u & 63;
    const int ln = l & 15;        // A row within 16-tile / D col lane
    const int q  = l >> 4;        // k-quad 0..3

    const float* __restrict__ xin = inp + (size_t)b * (NODES * FEAT);
    const float* __restrict__ wb  = weights + (size_t)idx[b] * (NODES * NODES);

    // ---- X global loads first (independent of idx gather)
    const float4* x4 = (const float4*)xin;
    const int fq = u & 7;            // feature quad
    const int k0 = (u >> 3) * 2;     // 0,2,...,126
    const float4 v0 = x4[k0 * 8 + fq];
    const float4 v1 = x4[(k0 + 1) * 8 + fq];

    // ---- async DMA: stage W k-columns [p*64, p*64+64) into wc
    auto stage_w = [&](int p) {
        #pragma unroll
        for (int s = 0; s < 4; ++s) {
            const int i    = s * 512 + u;        // dest seg 0..2047
            const int row  = i >> 4;
            const int lseg = i & 15;
            const int gseg = (lseg - row) & 15;  // inverse of read-side rotation
            gvoid* g   = (gvoid*)(wb + row * NODES + p * 64 + gseg * 4);
            svoid* dst = (svoid*)(wc + s * 512 + w * 64);  // wave-uniform base; HW adds lane*16
            __builtin_amdgcn_global_load_lds(g, dst, 16, 0, 0);
        }
    };

    stage_w(0);

    // ---- transpose-pack X into xt (bf16)
    {
        const float pv0[4] = {v0.x, v0.y, v0.z, v0.w};
        const float pv1[4] = {v1.x, v1.y, v1.z, v1.w};
        #pragma unroll
        for (int i = 0; i < 4; ++i)
            *(unsigned*)(&xt[(fq * 4 + i) * XPAD + k0]) = pk_bf16(pv0[i], pv1[i]);
    }
    __syncthreads();   // drains W DMA (vmcnt) + xt writes (lgkmcnt)

    f32x4 acc[2] = {};
    const int arow = 16 * w + ln;

    #pragma unroll
    for (int p = 0; p < 2; ++p) {
        if (p == 1) {
            __syncthreads();   // all reads of chunk0 done
            stage_w(1);
            __syncthreads();   // chunk1 resident
        }
        #pragma unroll
        for (int kcp = 0; kcp < 2; ++kcp) {
            const int kb = 2 * p + kcp;          // global 32-k block 0..3
            const int g0 = kcp * 8 + q * 2;      // within-chunk seg of lane's 32B A strip
            const float4 alo = wc[arow * 16 + ((g0 + 0 + arow) & 15)];
            const float4 ahi = wc[arow * 16 + ((g0 + 1 + arow) & 15)];
            const bf16x8 afr = cvt_frag(alo, ahi);
            #pragma unroll
            for (int nt = 0; nt < 2; ++nt) {
                const bf16x8 bfr = *(const bf16x8*)(&xt[(16 * nt + ln) * XPAD + kb * 32 + q * 8]);
                acc[nt] = __builtin_amdgcn_mfma_f32_16x16x32_bf16(afr, bfr, acc[nt], 0, 0, 0);
            }
        }
    }

    // ---- store: D layout col=lane&15, row=(lane>>4)*4+reg (m89-verified)
    float* ob = out + (size_t)b * (NODES * FEAT);
    #pragma unroll
    for (int nt = 0; nt < 2; ++nt)
        #pragma unroll
        for (int reg = 0; reg < 4; ++reg)
            ob[(16 * w + q * 4 + reg) * FEAT + 16 * nt + ln] = acc[nt][reg];
}

extern "C" void kernel_launch(void* const* d_in, const int* in_sizes, int n_in,
                              void* d_out, int out_size, void* d_ws, size_t ws_size,
                              hipStream_t stream) {
    const float* inp = (const float*)d_in[0];
    const float* wts = (const float*)d_in[1];
    const int*   idx = (const int*)d_in[2];
    float* outp = (float*)d_out;
    const int B = in_sizes[2];   // 1024
    hipLaunchKernelGGL(blockdiag_mm, dim3(B), dim3(512), 0, stream,
                       inp, wts, idx, outp);
}